// Round 27
// baseline (390.411 us; speedup 1.0000x reference)
//
#include <hip/hip_runtime.h>
#include <math.h>

#define Bn 16
#define Cn 64
#define Hn 192
#define Wn 192
#define NPIX (Bn * Cn * Hn * Wn)   // 37748736
#define NBLKS 512
#define WCOLS 98
#define SLOTB (WCOLS * 128)        // 12544 B per window row-slot

typedef short bf16x8 __attribute__((ext_vector_type(8)));
typedef float f32x16 __attribute__((ext_vector_type(16)));

// A-operand fragments, contiguous per (sp, ks, mhalf): g_Mf[(sp*4+ks)*2+mh][lane][8 bf16].
// Lane l holds M row (l&31)+32*mh, channels (2ks+(l>>5))*8+e. 72 KB -> L2/L3-resident;
// compute reads one coalesced 1024B global_load_dwordx4 per fragment. (R26-verified.)
__device__ __align__(16) unsigned short g_Mf[9 * 4 * 2 * 512];
__device__ __align__(16) float g_b2[64];

static __device__ __forceinline__ unsigned short f2bf(float f) {
    union { float f; unsigned u; } x; x.f = f;
    unsigned r = x.u + 0x7fffu + ((x.u >> 16) & 1u);   // RNE
    return (unsigned short)(r >> 16);
}

__global__ void acdc_precompute(const float* __restrict__ cw, const float* __restrict__ A,
                                const float* __restrict__ D, const float* __restrict__ bias,
                                const int* __restrict__ perm) {
    __shared__ float mre[64];
    int p = blockIdx.x;      // M row = output channel 0..63
    int t = threadIdx.x;
    if (t < 64) {
        float re = 0.f;
        for (int k = 0; k < 64; ++k) {
            int a = (k * t) & 63;
            re += D[k] * cosf((float)a * 0.0981747704246810387f);  // pi/32
        }
        mre[t] = re;
    }
    __syncthreads();
    int pp = perm[p];
    int mh = p >> 5, l31p = p & 31;
    for (int k0 = t; k0 < 576; k0 += 256) {
        int sp = k0 >> 6, c = k0 & 63;
        int g = c >> 3, cil = c & 7;
        float val = 0.f;
        for (int o = 0; o < 8; ++o) {
            int oc = g * 8 + o;
            float gco = mre[(pp - oc + 64) & 63] * A[oc] * (0.125f / 64.0f);
            val += gco * cw[(oc * 8 + cil) * 9 + sp];
        }
        int ks = c >> 4, lh = (c >> 3) & 1, e = c & 7;
        int lane = (lh << 5) | l31p;
        g_Mf[((((sp << 2) + ks) * 2 + mh) << 9) + (lane << 3) + e] = f2bf(val);
    }
    if (p == 0 && t < 64)
        g_b2[t] = bias[perm[t]] * 0.125f;
}

// R23 skeleton (512 thr, 8 waves, proven clean codegen @124 VGPR) with M moved
// OUT of LDS into L2 (g_Mf coalesced fragments, R26-verified layout). LDS = 50 KB
// window only -> (512,4) gives 2 blocks/CU = 16 waves/CU (2x R23's occupancy)
// with R23's 3.6x-reduced LDS read volume. Block = image x 12-row band x half
// width; 2-row steps, 4-slot circular window; compute = 6 waves x 32x32x16 MFMA.
__global__ __launch_bounds__(512, 4)
void acdc_main(const float* __restrict__ x, float* __restrict__ out) {
    __shared__ __align__(16) unsigned char xsb[4 * SLOTB];       // 50176 B

    int tid = threadIdx.x;
    int lane = tid & 63, wv = tid >> 6;   // 8 waves
    // bijective XCD swizzle (512 % 8 == 0)
    int Lb = (blockIdx.x & 7) * (NBLKS / 8) + (blockIdx.x >> 3);
    int bb = Lb >> 5;                 // image
    int band = (Lb >> 1) & 15;        // 12-row band
    int half = Lb & 1;                // width half
    int h0 = band * 12;               // h0 % 4 == 0
    int cbase = half * 96;

    const float* xb = x + (size_t)bb * Cn * Hn * Wn;

    // ---- prologue: rows h0-1..h0+2 -> slots 0..3 (fused load+write) ----
    for (int k = 0; k < 7; ++k) {
        int idx = tid + (k << 9);
        if (idx >= 3328) break;
        int cp_lo = idx & 3;
        int f = (idx >> 2) % 26;
        int r4 = idx / 104;
        int rr = r4 & 3, cp_hi = r4 >> 2;
        int cp = cp_hi * 4 + cp_lo;
        int gi = h0 - 1 + rr;
        int gc0 = cbase + 4 * f - 4;
        float av[4] = {0.f,0.f,0.f,0.f}, bv[4] = {0.f,0.f,0.f,0.f};
        bool giok = (unsigned)gi < (unsigned)Hn;
        const float* r0 = xb + ((size_t)(2 * cp) * Hn + (giok ? gi : 0)) * Wn;
        const float* r1 = r0 + Hn * Wn;
        if (giok) {
            if (gc0 >= 0 && gc0 <= Wn - 4) {
                float4 a = *(const float4*)(r0 + gc0);
                float4 b = *(const float4*)(r1 + gc0);
                av[0]=a.x; av[1]=a.y; av[2]=a.z; av[3]=a.w;
                bv[0]=b.x; bv[1]=b.y; bv[2]=b.z; bv[3]=b.w;
            } else {
                #pragma unroll
                for (int j = 0; j < 4; ++j) {
                    int gc = gc0 + j;
                    if ((unsigned)gc < (unsigned)Wn) { av[j] = r0[gc]; bv[j] = r1[gc]; }
                }
            }
        }
        int slot = rr;                       // slot(gi) = (gi+1)&3 = rr  (h0%4==0)
        int chunk = cp >> 2, sub = (cp & 3) * 4;
        #pragma unroll
        for (int j = 0; j < 4; ++j) {
            int c2 = 4 * f + j - 3;
            if ((unsigned)c2 >= (unsigned)WCOLS) continue;
            unsigned u;
            asm("v_cvt_pk_bf16_f32 %0, %1, %2" : "=v"(u) : "v"(av[j]), "v"(bv[j]));
            int key = (c2 + (c2 >> 3) + 3 * slot) & 7;
            *(unsigned*)(xsb + slot * SLOTB + c2 * 128 + ((chunk ^ key) << 4) + sub) = u;
        }
    }
    __syncthreads();   // initial 4-row window ready

    int l31 = lane & 31, lh = lane >> 5;

    float4 va[4], vb[4];
    for (int t = 0; t < 6; ++t) {
        int hb = h0 + 2 * t;

        // ---- xload: rows hb+3, hb+4 to regs (retire under compute) ----
        if (t < 5) {
            #pragma unroll
            for (int k = 0; k < 4; ++k) {
                int idx = tid + (k << 9);
                va[k] = (float4){0.f,0.f,0.f,0.f};
                vb[k] = (float4){0.f,0.f,0.f,0.f};
                if (idx >= 1664) continue;
                int cp_lo = idx & 3;
                int f = (idx >> 2) % 26;
                int r2 = idx / 104;
                int rr = r2 & 1, cp_hi = r2 >> 1;
                int cp = cp_hi * 4 + cp_lo;
                int gi = hb + 3 + rr;
                int gc0 = cbase + 4 * f - 4;
                bool giok = (unsigned)gi < (unsigned)Hn;
                const float* r0 = xb + ((size_t)(2 * cp) * Hn + (giok ? gi : 0)) * Wn;
                const float* r1 = r0 + Hn * Wn;
                if (giok) {
                    if (gc0 >= 0 && gc0 <= Wn - 4) {
                        va[k] = *(const float4*)(r0 + gc0);
                        vb[k] = *(const float4*)(r1 + gc0);
                    } else {
                        float t0[4] = {0,0,0,0}, t1[4] = {0,0,0,0};
                        #pragma unroll
                        for (int j = 0; j < 4; ++j) {
                            int gc = gc0 + j;
                            if ((unsigned)gc < (unsigned)Wn) { t0[j] = r0[gc]; t1[j] = r1[gc]; }
                        }
                        va[k] = (float4){t0[0], t0[1], t0[2], t0[3]};
                        vb[k] = (float4){t1[0], t1[1], t1[2], t1[3]};
                    }
                }
            }
        }

        // ---- compute: 6 active waves; wave = (row rr, 32px tile nt); both m-halves ----
        if (wv < 6) {
            int rr = wv & 1;
            int nt = wv >> 1;
            f32x16 acc0, acc1;
            #pragma unroll
            for (int e = 0; e < 16; ++e) { acc0[e] = 0.f; acc1[e] = 0.f; }

            #pragma unroll
            for (int sp = 0; sp < 9; ++sp) {
                const int dy = sp / 3, dx = sp % 3;
                int v = (2 * t + rr + dy) & 3;         // slot of input row hb+rr+dy-1
                int c2 = nt * 32 + l31 + dx;
                int key = (c2 + (c2 >> 3) + 3 * v) & 7;
                const unsigned char* bbase = xsb + v * SLOTB + c2 * 128;
                const unsigned char* afrag = (const unsigned char*)g_Mf + sp * 8192 + lane * 16;
                #pragma unroll
                for (int ks = 0; ks < 4; ++ks) {
                    int o = 2 * ks + lh;               // k-octet (channel octet)
                    bf16x8 bfr = *(const bf16x8*)(bbase + ((o ^ key) << 4));
                    bf16x8 am0 = *(const bf16x8*)(afrag + ks * 2048);
                    bf16x8 am1 = *(const bf16x8*)(afrag + ks * 2048 + 1024);
                    __builtin_amdgcn_s_setprio(1);
                    acc0 = __builtin_amdgcn_mfma_f32_32x32x16_bf16(am0, bfr, acc0, 0, 0, 0);
                    acc1 = __builtin_amdgcn_mfma_f32_32x32x16_bf16(am1, bfr, acc1, 0, 0, 0);
                    __builtin_amdgcn_s_setprio(0);
                }
            }

            // ---- epilogue: +bias; C/D: ch = (r&3)+8*(r>>2)+4*lh, px = l31 ----
            int h = hb + rr;
            int pxg = cbase + nt * 32 + l31;
            #pragma unroll
            for (int r = 0; r < 16; ++r) {
                int chq = (r & 3) + 8 * (r >> 2) + 4 * lh;
                out[(((size_t)(bb * Cn + chq)) * Hn + h) * Wn + pxg]      = acc0[r] + g_b2[chq];
                out[(((size_t)(bb * Cn + 32 + chq)) * Hn + h) * Wn + pxg] = acc1[r] + g_b2[32 + chq];
            }
        }

        __syncthreads();                  // all window reads for this step done

        // ---- xwrite: rows hb+3, hb+4 into retiring slots ----
        if (t < 5) {
            #pragma unroll
            for (int k = 0; k < 4; ++k) {
                int idx = tid + (k << 9);
                if (idx >= 1664) continue;
                int cp_lo = idx & 3;
                int f = (idx >> 2) % 26;
                int r2 = idx / 104;
                int rr = r2 & 1, cp_hi = r2 >> 1;
                int cp = cp_hi * 4 + cp_lo;
                int vslot = (2 * t + rr) & 3;          // slot(hb+3+rr)
                int chunk = cp >> 2, sub = (cp & 3) * 4;
                float v0[4] = {va[k].x, va[k].y, va[k].z, va[k].w};
                float v1[4] = {vb[k].x, vb[k].y, vb[k].z, vb[k].w};
                #pragma unroll
                for (int j = 0; j < 4; ++j) {
                    int c2 = 4 * f + j - 3;
                    if ((unsigned)c2 >= (unsigned)WCOLS) continue;
                    unsigned u;
                    asm("v_cvt_pk_bf16_f32 %0, %1, %2" : "=v"(u) : "v"(v0[j]), "v"(v1[j]));
                    int key = (c2 + (c2 >> 3) + 3 * vslot) & 7;
                    *(unsigned*)(xsb + vslot * SLOTB + c2 * 128 + ((chunk ^ key) << 4) + sub) = u;
                }
            }
        }
        __syncthreads();                  // publish new rows
    }
}

extern "C" void kernel_launch(void* const* d_in, const int* in_sizes, int n_in,
                              void* d_out, int out_size, void* d_ws, size_t ws_size,
                              hipStream_t stream) {
    const float* x    = (const float*)d_in[0];
    const float* cw   = (const float*)d_in[1];
    const float* A    = (const float*)d_in[2];
    const float* D    = (const float*)d_in[3];
    const float* bias = (const float*)d_in[4];
    const int*   perm = (const int*)d_in[5];

    acdc_precompute<<<dim3(64), dim3(256), 0, stream>>>(cw, A, D, bias, perm);
    acdc_main<<<dim3(NBLKS), dim3(512), 0, stream>>>(x, (float*)d_out);
}